// Round 1
// baseline (1113.572 us; speedup 1.0000x reference)
//
#include <hip/hip_runtime.h>
#include <math.h>

#define N_NODES 25000
#define N_EDGES 400000
#define FEAT 128
#define HID 64
#define HEADS 4
#define HH 256   // HEADS*HID
#define NUM_GRAPHS 64

__device__ __forceinline__ float lrelu(float x){ return x > 0.f ? x : 0.2f*x; }

__device__ __forceinline__ void atomicMaxF(float* a, float v){
  if (v >= 0.f) atomicMax((int*)a, __float_as_int(v));
  else          atomicMin((unsigned int*)a, __float_as_uint(v));
}

// out[i][j] = sum_k X[i][k]*W[k][j] (+ bias[j]); one wave per node, W in LDS.
template<int K>
__global__ __launch_bounds__(256) void node_gemm64(
    const float* __restrict__ X, const float* __restrict__ W,
    const float* __restrict__ bias, float* __restrict__ out)
{
  __shared__ float wsm[K*HID];          // K=256 -> exactly 64 KB
  for (int i = threadIdx.x; i < K*HID; i += 256) wsm[i] = W[i];
  __syncthreads();
  const int j  = threadIdx.x & 63;      // output col / lane
  const int ln = threadIdx.x >> 6;      // wave id = local node
  const float b = bias ? bias[j] : 0.f;
  const int ngroups = (N_NODES + 3) / 4;
  for (int grp = blockIdx.x; grp < ngroups; grp += gridDim.x){
    const int node = grp*4 + ln;
    if (node >= N_NODES) continue;
    float xv[K/64];
    #pragma unroll
    for (int q = 0; q < K/64; q++) xv[q] = X[node*K + q*64 + j];
    float acc = b;
    #pragma unroll
    for (int q = 0; q < K/64; q++){
      #pragma unroll 16
      for (int kk = 0; kk < 64; kk++){
        float xb = __shfl(xv[q], kk, 64);
        acc += xb * wsm[(q*64+kk)*HID + j];
      }
    }
    out[node*HID + j] = acc;
  }
}

// acc[dst] += feat[src], 64 floats per edge
__global__ __launch_bounds__(256) void k_scatter64(
    const int* __restrict__ src, const int* __restrict__ dst,
    const float* __restrict__ feat, float* __restrict__ acc)
{
  int idx = blockIdx.x*256 + threadIdx.x;
  if (idx >= N_EDGES*HID) return;
  int e = idx >> 6, c = idx & 63;
  int s = src[e], d = dst[e];
  atomicAdd(&acc[d*HID + c], feat[s*HID + c]);
}

// h1 = relu(h1_acc); xl = h1 @ Wg; a_s/a_d head dots; m init = self-loop e
__global__ __launch_bounds__(256) void k3_gat_transform(
    const float* __restrict__ h1_acc, const float* __restrict__ Wg,
    const float* __restrict__ att_src, const float* __restrict__ att_dst,
    float* __restrict__ xl, float* __restrict__ a_s, float* __restrict__ a_d,
    float* __restrict__ m)
{
  __shared__ float wg[HID*HH];          // exactly 64 KB
  for (int i = threadIdx.x; i < HID*HH; i += 256) wg[i] = Wg[i];
  __syncthreads();
  const int hc = threadIdx.x, h = hc >> 6, c = hc & 63;
  const float asv = att_src[h*HID + c];
  const float adv = att_dst[h*HID + c];
  for (int node = blockIdx.x; node < N_NODES; node += gridDim.x){
    float hval = fmaxf(h1_acc[node*HID + c], 0.f);   // each wave holds the row
    float acc = 0.f;
    #pragma unroll 16
    for (int k = 0; k < HID; k++){
      float hk = __shfl(hval, k, 64);
      acc += hk * wg[k*HH + hc];
    }
    xl[node*HH + hc] = acc;
    float s1 = acc * asv, s2 = acc * adv;
    #pragma unroll
    for (int off = 32; off > 0; off >>= 1){
      s1 += __shfl_down(s1, off, 64);
      s2 += __shfl_down(s2, off, 64);
    }
    if (c == 0){
      a_s[node*HEADS + h] = s1;
      a_d[node*HEADS + h] = s2;
      m[node*HEADS + h]   = lrelu(s1 + s2);   // self-loop initializes the max
    }
  }
}

__global__ __launch_bounds__(256) void k4_edge_max(
    const int* __restrict__ src, const int* __restrict__ dst,
    const float* __restrict__ a_s, const float* __restrict__ a_d,
    float* __restrict__ m)
{
  int idx = blockIdx.x*256 + threadIdx.x;
  if (idx >= N_EDGES*HEADS) return;
  int e = idx >> 2, h = idx & 3;
  int s = src[e], d = dst[e];
  float v = lrelu(a_s[s*HEADS+h] + a_d[d*HEADS+h]);
  atomicMaxF(&m[d*HEADS+h], v);
}

// self-loop contribution: denom = p_self; h2_acc = p_self * xl
__global__ __launch_bounds__(256) void k5_self_init(
    const float* __restrict__ xl, const float* __restrict__ a_s,
    const float* __restrict__ a_d, const float* __restrict__ m,
    float* __restrict__ denom, float* __restrict__ h2_acc)
{
  int idx = blockIdx.x*256 + threadIdx.x;
  if (idx >= N_NODES*HH) return;
  int i = idx >> 8, hc = idx & 255, h = hc >> 6;
  float p = __expf(lrelu(a_s[i*HEADS+h] + a_d[i*HEADS+h]) - m[i*HEADS+h]);
  if ((hc & 63) == 0) denom[i*HEADS+h] = p;
  h2_acc[idx] = p * xl[idx];
}

// per-edge p, accumulate denom
__global__ __launch_bounds__(256) void k_edge_p(
    const int* __restrict__ src, const int* __restrict__ dst,
    const float* __restrict__ a_s, const float* __restrict__ a_d,
    const float* __restrict__ m, float* __restrict__ denom,
    float* __restrict__ p_e)
{
  int idx = blockIdx.x*256 + threadIdx.x;
  if (idx >= N_EDGES*HEADS) return;
  int e = idx >> 2, h = idx & 3;
  int s = src[e], d = dst[e];
  float p = __expf(lrelu(a_s[s*HEADS+h] + a_d[d*HEADS+h]) - m[d*HEADS+h]);
  p_e[idx] = p;
  atomicAdd(&denom[d*HEADS+h], p);
}

// h2_acc[dst] += p * xl[src]  (one block = one edge, 256 floats)
__global__ __launch_bounds__(256) void k6_scatter_gat(
    const int* __restrict__ src, const int* __restrict__ dst,
    const float* __restrict__ p_e, const float* __restrict__ xl,
    float* __restrict__ h2_acc)
{
  int e = blockIdx.x;
  int hc = threadIdx.x, h = hc >> 6;
  int s = src[e], d = dst[e];
  float p = p_e[e*HEADS + h];
  atomicAdd(&h2_acc[d*HH + hc], p * xl[s*HH + hc]);
}

// h2 = relu(h2_acc/denom + bg), in place
__global__ __launch_bounds__(256) void k7_gat_final(
    const float* __restrict__ denom, const float* __restrict__ bg,
    float* __restrict__ h2_acc)
{
  int idx = blockIdx.x*256 + threadIdx.x;
  if (idx >= N_NODES*HH) return;
  int i = idx >> 8, hc = idx & 255, h = hc >> 6;
  float v = h2_acc[idx] / denom[i*HEADS+h] + bg[hc];
  h2_acc[idx] = fmaxf(v, 0.f);
}

// g[batch[i]] += relu(h3_acc[i])
__global__ __launch_bounds__(256) void k_pool(
    const float* __restrict__ h3_acc, const int* __restrict__ batch,
    float* __restrict__ g)
{
  int idx = blockIdx.x*256 + threadIdx.x;
  if (idx >= N_NODES*HID) return;
  int i = idx >> 6, j = idx & 63;
  float v = fmaxf(h3_acc[idx], 0.f);
  atomicAdd(&g[batch[i]*HID + j], v);
}

// fc head: relu(g@W1+b1) @ W2 + b2 -> sigmoid
__global__ __launch_bounds__(256) void k_head(
    const float* __restrict__ g, const float* __restrict__ W1,
    const float* __restrict__ b1, const float* __restrict__ W2,
    const float* __restrict__ b2, float* __restrict__ out)
{
  __shared__ float gs[NUM_GRAPHS*HID];
  __shared__ float hh[NUM_GRAPHS*HID];
  for (int i = threadIdx.x; i < NUM_GRAPHS*HID; i += 256) gs[i] = g[i];
  __syncthreads();
  for (int t = threadIdx.x; t < NUM_GRAPHS*HID; t += 256){
    int b = t >> 6, j = t & 63;
    float acc = b1[j];
    for (int k = 0; k < HID; k++) acc += gs[b*HID+k]*W1[k*HID+j];
    hh[t] = fmaxf(acc, 0.f);
  }
  __syncthreads();
  for (int t = threadIdx.x; t < NUM_GRAPHS*2; t += 256){
    int b = t >> 1, c = t & 1;
    float acc = b2[c];
    for (int k = 0; k < HID; k++) acc += hh[b*HID+k]*W2[k*2+c];
    out[t] = 1.f / (1.f + __expf(-acc));
  }
}

extern "C" void kernel_launch(void* const* d_in, const int* in_sizes, int n_in,
                              void* d_out, int out_size, void* d_ws, size_t ws_size,
                              hipStream_t stream)
{
  const float* x       = (const float*)d_in[0];
  const int*   ei      = (const int*)d_in[1];
  const int*   batch   = (const int*)d_in[2];
  const float* W1_rel  = (const float*)d_in[3];
  const float* b1      = (const float*)d_in[4];
  const float* W1_root = (const float*)d_in[5];
  const float* Wg      = (const float*)d_in[6];
  const float* att_src = (const float*)d_in[7];
  const float* att_dst = (const float*)d_in[8];
  const float* bg      = (const float*)d_in[9];
  const float* W5_rel  = (const float*)d_in[10];
  const float* b5      = (const float*)d_in[11];
  const float* W5_root = (const float*)d_in[12];
  const float* W_fc1   = (const float*)d_in[13];
  const float* b_fc1   = (const float*)d_in[14];
  const float* W_fc2   = (const float*)d_in[15];
  const float* b_fc2   = (const float*)d_in[16];
  const int* src = ei;
  const int* dst = ei + N_EDGES;

  float* ws     = (float*)d_ws;
  float* xr     = ws;             // N*64   (reused as h2r for conv5)
  float* h1_acc = ws +  1600000;  // N*64   (reused as h3_acc)
  float* xl     = ws +  3200000;  // N*256
  float* a_s    = ws +  9600000;  // N*4
  float* a_d    = ws +  9700000;  // N*4
  float* mbuf   = ws +  9800000;  // N*4
  float* denom  = ws +  9900000;  // N*4
  float* h2_acc = ws + 10000000;  // N*256
  float* p_e    = ws + 16400000;  // E*4
  float* g      = ws + 18000000;  // 64*64
  float* out    = (float*)d_out;

  // conv1: xr = x@W1_rel ; h1_acc = x@W1_root + b1 ; h1_acc += segsum(xr[src] -> dst)
  node_gemm64<FEAT><<<1024,256,0,stream>>>(x, W1_rel, nullptr, xr);
  node_gemm64<FEAT><<<1024,256,0,stream>>>(x, W1_root, b1, h1_acc);
  k_scatter64<<<(N_EDGES*HID+255)/256,256,0,stream>>>(src, dst, xr, h1_acc);

  // GAT
  k3_gat_transform<<<1024,256,0,stream>>>(h1_acc, Wg, att_src, att_dst, xl, a_s, a_d, mbuf);
  k4_edge_max<<<(N_EDGES*HEADS+255)/256,256,0,stream>>>(src, dst, a_s, a_d, mbuf);
  k5_self_init<<<(N_NODES*HH+255)/256,256,0,stream>>>(xl, a_s, a_d, mbuf, denom, h2_acc);
  k_edge_p<<<(N_EDGES*HEADS+255)/256,256,0,stream>>>(src, dst, a_s, a_d, mbuf, denom, p_e);
  k6_scatter_gat<<<N_EDGES,256,0,stream>>>(src, dst, p_e, xl, h2_acc);
  k7_gat_final<<<(N_NODES*HH+255)/256,256,0,stream>>>(denom, bg, h2_acc);

  // conv5 (input h2 = h2_acc, already relu'd)
  node_gemm64<HH><<<1024,256,0,stream>>>(h2_acc, W5_rel, nullptr, xr);
  node_gemm64<HH><<<1024,256,0,stream>>>(h2_acc, W5_root, b5, h1_acc);
  k_scatter64<<<(N_EDGES*HID+255)/256,256,0,stream>>>(src, dst, xr, h1_acc);

  // pool + head
  hipMemsetAsync(g, 0, NUM_GRAPHS*HID*sizeof(float), stream);
  k_pool<<<(N_NODES*HID+255)/256,256,0,stream>>>(h1_acc, batch, g);
  k_head<<<1,256,0,stream>>>(g, W_fc1, b_fc1, W_fc2, b_fc2, out);
}

// Round 2
// 832.175 us; speedup vs baseline: 1.3381x; 1.3381x over previous
//
#include <hip/hip_runtime.h>
#include <math.h>

#define N_NODES 25000
#define N_EDGES 400000
#define FEAT 128
#define HID 64
#define HEADS 4
#define HH 256   // HEADS*HID
#define NUM_GRAPHS 64

__device__ __forceinline__ float lrelu(float x){ return x > 0.f ? x : 0.2f*x; }

// ---------------- node GEMM: out[i][j] = sum_k X[i][k]*W[k][j] (+bias) -------
template<int K>
__global__ __launch_bounds__(256) void node_gemm64(
    const float* __restrict__ X, const float* __restrict__ W,
    const float* __restrict__ bias, float* __restrict__ out)
{
  __shared__ float wsm[K*HID];          // K=256 -> exactly 64 KB
  for (int i = threadIdx.x; i < K*HID; i += 256) wsm[i] = W[i];
  __syncthreads();
  const int j  = threadIdx.x & 63;
  const int ln = threadIdx.x >> 6;
  const float b = bias ? bias[j] : 0.f;
  const int ngroups = (N_NODES + 3) / 4;
  for (int grp = blockIdx.x; grp < ngroups; grp += gridDim.x){
    const int node = grp*4 + ln;
    if (node >= N_NODES) continue;
    float xv[K/64];
    #pragma unroll
    for (int q = 0; q < K/64; q++) xv[q] = X[node*K + q*64 + j];
    float acc = b;
    #pragma unroll
    for (int q = 0; q < K/64; q++){
      #pragma unroll 16
      for (int kk = 0; kk < 64; kk++){
        float xb = __shfl(xv[q], kk, 64);
        acc += xb * wsm[(q*64+kk)*HID + j];
      }
    }
    out[node*HID + j] = acc;
  }
}

// ---------------- CSR build --------------------------------------------------
__global__ __launch_bounds__(256) void k_hist(const int* __restrict__ dst, int* __restrict__ deg)
{
  int e = blockIdx.x*256 + threadIdx.x;
  if (e < N_EDGES) atomicAdd(&deg[dst[e]], 1);
}

// single-block exclusive scan: deg[0..N) -> row_start[0..N], cursor copy
__global__ __launch_bounds__(1024) void k_scan(const int* __restrict__ deg,
                                               int* __restrict__ row_start,
                                               int* __restrict__ cursor)
{
  const int SEG = (N_NODES + 1023) / 1024;     // 25
  const int t = threadIdx.x, lane = t & 63, wid = t >> 6;
  int begin = t*SEG, end = begin+SEG; if (end > N_NODES) end = N_NODES;
  if (begin > N_NODES) begin = N_NODES;
  int lsum = 0;
  for (int i = begin; i < end; i++) lsum += deg[i];
  // intra-wave inclusive scan
  int v = lsum;
  #pragma unroll
  for (int off = 1; off < 64; off <<= 1){
    int u = __shfl_up(v, off, 64);
    if (lane >= off) v += u;
  }
  __shared__ int wsum[16];
  __shared__ int wpre[16];
  if (lane == 63) wsum[wid] = v;
  __syncthreads();
  if (t == 0){
    int run = 0;
    for (int w = 0; w < 16; w++){ wpre[w] = run; run += wsum[w]; }
  }
  __syncthreads();
  int excl = wpre[wid] + v - lsum;   // exclusive prefix of this thread's segment
  int run = excl;
  for (int i = begin; i < end; i++){
    row_start[i] = run; cursor[i] = run;
    run += deg[i];
  }
  if (t == 0) row_start[N_NODES] = N_EDGES;
}

__global__ __launch_bounds__(256) void k_fill(const int* __restrict__ src,
                                              const int* __restrict__ dst,
                                              int* __restrict__ cursor,
                                              int* __restrict__ perm_src)
{
  int e = blockIdx.x*256 + threadIdx.x;
  if (e >= N_EDGES) return;
  int pos = atomicAdd(&cursor[dst[e]], 1);
  perm_src[pos] = src[e];
}

// ---------------- gather aggregation: out = relu(root + sum_in feat[src]) ----
__global__ __launch_bounds__(256) void k_agg_gather64(
    const int* __restrict__ row_start, const int* __restrict__ perm_src,
    const float* __restrict__ feat, const float* __restrict__ root,
    float* __restrict__ out)
{
  int node = blockIdx.x*4 + (threadIdx.x >> 6);
  if (node >= N_NODES) return;
  int j = threadIdx.x & 63;
  int s0 = row_start[node], s1 = row_start[node+1];
  float acc = root[node*HID + j];
  for (int e = s0; e < s1; e++){
    int s = perm_src[e];
    acc += feat[s*HID + j];
  }
  out[node*HID + j] = fmaxf(acc, 0.f);
}

// ---------------- GAT: transform + attention logits --------------------------
__global__ __launch_bounds__(256) void k3_gat_transform(
    const float* __restrict__ h1, const float* __restrict__ Wg,
    const float* __restrict__ att_src, const float* __restrict__ att_dst,
    float* __restrict__ xl, float* __restrict__ a_s, float* __restrict__ a_d)
{
  __shared__ float wg[HID*HH];          // exactly 64 KB
  for (int i = threadIdx.x; i < HID*HH; i += 256) wg[i] = Wg[i];
  __syncthreads();
  const int hc = threadIdx.x, h = hc >> 6, c = hc & 63;
  const float asv = att_src[h*HID + c];
  const float adv = att_dst[h*HID + c];
  for (int node = blockIdx.x; node < N_NODES; node += gridDim.x){
    float hval = h1[node*HID + c];      // already relu'd; each wave holds the row
    float acc = 0.f;
    #pragma unroll 16
    for (int k = 0; k < HID; k++){
      float hk = __shfl(hval, k, 64);
      acc += hk * wg[k*HH + hc];
    }
    xl[node*HH + hc] = acc;
    float s1 = acc * asv, s2 = acc * adv;
    #pragma unroll
    for (int off = 32; off > 0; off >>= 1){
      s1 += __shfl_down(s1, off, 64);
      s2 += __shfl_down(s2, off, 64);
    }
    if (c == 0){
      a_s[node*HEADS + h] = s1;
      a_d[node*HEADS + h] = s2;
    }
  }
}

// ---------------- fused per-node GAT softmax + aggregate ---------------------
__global__ __launch_bounds__(256) void k_gat_node(
    const int* __restrict__ row_start, const int* __restrict__ perm_src,
    const float* __restrict__ xl, const float* __restrict__ a_s,
    const float* __restrict__ a_d, const float* __restrict__ bg,
    float* __restrict__ out)
{
  const int d = blockIdx.x;
  const int hc = threadIdx.x, h = hc >> 6;
  const int s0 = row_start[d], s1 = row_start[d+1];
  const float ad = a_d[d*HEADS + h];
  const float eself = lrelu(a_s[d*HEADS + h] + ad);
  float m = eself;
  for (int e = s0; e < s1; e++){
    int s = perm_src[e];
    float v = lrelu(a_s[s*HEADS + h] + ad);
    m = fmaxf(m, v);
  }
  float p = __expf(eself - m);
  float denom = p;
  float acc = p * xl[d*HH + hc];
  for (int e = s0; e < s1; e++){
    int s = perm_src[e];
    float v = lrelu(a_s[s*HEADS + h] + ad);
    p = __expf(v - m);
    denom += p;
    acc += p * xl[s*HH + hc];
  }
  out[d*HH + hc] = fmaxf(acc/denom + bg[hc], 0.f);
}

// ---------------- pool + head ------------------------------------------------
__global__ __launch_bounds__(256) void k_pool(
    const float* __restrict__ h3, const int* __restrict__ batch,
    float* __restrict__ g)
{
  int idx = blockIdx.x*256 + threadIdx.x;
  if (idx >= N_NODES*HID) return;
  int i = idx >> 6, j = idx & 63;
  atomicAdd(&g[batch[i]*HID + j], h3[idx]);   // h3 already relu'd
}

__global__ __launch_bounds__(256) void k_head(
    const float* __restrict__ g, const float* __restrict__ W1,
    const float* __restrict__ b1, const float* __restrict__ W2,
    const float* __restrict__ b2, float* __restrict__ out)
{
  __shared__ float gs[NUM_GRAPHS*HID];
  __shared__ float hh[NUM_GRAPHS*HID];
  for (int i = threadIdx.x; i < NUM_GRAPHS*HID; i += 256) gs[i] = g[i];
  __syncthreads();
  for (int t = threadIdx.x; t < NUM_GRAPHS*HID; t += 256){
    int b = t >> 6, j = t & 63;
    float acc = b1[j];
    for (int k = 0; k < HID; k++) acc += gs[b*HID+k]*W1[k*HID+j];
    hh[t] = fmaxf(acc, 0.f);
  }
  __syncthreads();
  for (int t = threadIdx.x; t < NUM_GRAPHS*2; t += 256){
    int b = t >> 1, c = t & 1;
    float acc = b2[c];
    for (int k = 0; k < HID; k++) acc += hh[b*HID+k]*W2[k*2+c];
    out[t] = 1.f / (1.f + __expf(-acc));
  }
}

extern "C" void kernel_launch(void* const* d_in, const int* in_sizes, int n_in,
                              void* d_out, int out_size, void* d_ws, size_t ws_size,
                              hipStream_t stream)
{
  const float* x       = (const float*)d_in[0];
  const int*   ei      = (const int*)d_in[1];
  const int*   batch   = (const int*)d_in[2];
  const float* W1_rel  = (const float*)d_in[3];
  const float* b1      = (const float*)d_in[4];
  const float* W1_root = (const float*)d_in[5];
  const float* Wg      = (const float*)d_in[6];
  const float* att_src = (const float*)d_in[7];
  const float* att_dst = (const float*)d_in[8];
  const float* bg      = (const float*)d_in[9];
  const float* W5_rel  = (const float*)d_in[10];
  const float* b5      = (const float*)d_in[11];
  const float* W5_root = (const float*)d_in[12];
  const float* W_fc1   = (const float*)d_in[13];
  const float* b_fc1   = (const float*)d_in[14];
  const float* W_fc2   = (const float*)d_in[15];
  const float* b_fc2   = (const float*)d_in[16];
  const int* src = ei;
  const int* dst = ei + N_EDGES;

  float* ws   = (float*)d_ws;
  float* xr   = ws;                     // N*64   (slot A; reused by conv5 rel)
  float* hB   = ws +  1600000;          // N*64   (slot B: hroot -> h1 -> h3)
  float* xl   = ws +  3200000;          // N*256
  float* a_s  = ws +  9600000;          // N*4
  float* a_d  = ws +  9700000;          // N*4
  float* h2   = ws +  9800000;          // N*256
  float* g    = ws + 16200000;          // 64*64
  int*   ib   = (int*)(ws + 16210000);
  int* deg      = ib;                   // 25000
  int* row_st   = ib + 25000;           // 25001 (+pad)
  int* cursor   = ib + 50016;           // 25000
  int* perm_src = ib + 75016;           // 400000
  float* out  = (float*)d_out;

  // CSR build
  hipMemsetAsync(deg, 0, N_NODES*sizeof(int), stream);
  hipMemsetAsync(g, 0, NUM_GRAPHS*HID*sizeof(float), stream);
  k_hist<<<(N_EDGES+255)/256,256,0,stream>>>(dst, deg);
  k_scan<<<1,1024,0,stream>>>(deg, row_st, cursor);
  k_fill<<<(N_EDGES+255)/256,256,0,stream>>>(src, dst, cursor, perm_src);

  // conv1: xr = x@W1_rel ; hB = x@W1_root + b1 ; h1 = relu(hB + gather(xr)) in-place
  node_gemm64<FEAT><<<1024,256,0,stream>>>(x, W1_rel, nullptr, xr);
  node_gemm64<FEAT><<<1024,256,0,stream>>>(x, W1_root, b1, hB);
  k_agg_gather64<<<(N_NODES+3)/4,256,0,stream>>>(row_st, perm_src, xr, hB, hB);

  // GAT
  k3_gat_transform<<<1024,256,0,stream>>>(hB, Wg, att_src, att_dst, xl, a_s, a_d);
  k_gat_node<<<N_NODES,256,0,stream>>>(row_st, perm_src, xl, a_s, a_d, bg, h2);

  // conv5
  node_gemm64<HH><<<1024,256,0,stream>>>(h2, W5_rel, nullptr, xr);
  node_gemm64<HH><<<1024,256,0,stream>>>(h2, W5_root, b5, hB);
  k_agg_gather64<<<(N_NODES+3)/4,256,0,stream>>>(row_st, perm_src, xr, hB, hB);

  // pool + head
  k_pool<<<(N_NODES*HID+255)/256,256,0,stream>>>(hB, batch, g);
  k_head<<<1,256,0,stream>>>(g, W_fc1, b_fc1, W_fc2, b_fc2, out);
}

// Round 3
// 678.966 us; speedup vs baseline: 1.6401x; 1.2257x over previous
//
#include <hip/hip_runtime.h>
#include <math.h>

#define N_NODES 25000
#define N_EDGES 400000
#define FEAT 128
#define HID 64
#define HEADS 4
#define HH 256   // HEADS*HID
#define NUM_GRAPHS 64

__device__ __forceinline__ float lrelu(float x){ return x > 0.f ? x : 0.2f*x; }

// ---------------- node GEMM: out[i][j] = sum_k X[i][k]*W[k][j] (+bias) -------
template<int K>
__global__ __launch_bounds__(256) void node_gemm64(
    const float* __restrict__ X, const float* __restrict__ W,
    const float* __restrict__ bias, float* __restrict__ out)
{
  __shared__ float wsm[K*HID];          // K=256 -> exactly 64 KB
  for (int i = threadIdx.x; i < K*HID; i += 256) wsm[i] = W[i];
  __syncthreads();
  const int j  = threadIdx.x & 63;
  const int ln = threadIdx.x >> 6;
  const float b = bias ? bias[j] : 0.f;
  const int ngroups = (N_NODES + 3) / 4;
  for (int grp = blockIdx.x; grp < ngroups; grp += gridDim.x){
    const int node = grp*4 + ln;
    if (node >= N_NODES) continue;
    float xv[K/64];
    #pragma unroll
    for (int q = 0; q < K/64; q++) xv[q] = X[node*K + q*64 + j];
    float acc = b;
    #pragma unroll
    for (int q = 0; q < K/64; q++){
      #pragma unroll 16
      for (int kk = 0; kk < 64; kk++){
        float xb = __shfl(xv[q], kk, 64);
        acc += xb * wsm[(q*64+kk)*HID + j];
      }
    }
    out[node*HID + j] = acc;
  }
}

// conv1: both weight matrices in LDS, one x read, shared shuffles
__global__ __launch_bounds__(256) void node_gemm_dual128(
    const float* __restrict__ X, const float* __restrict__ Wa,
    const float* __restrict__ Wb, const float* __restrict__ bias_b,
    float* __restrict__ outa, float* __restrict__ outb)
{
  __shared__ float wa[FEAT*HID];  // 32KB
  __shared__ float wb[FEAT*HID];  // 32KB
  for (int i = threadIdx.x; i < FEAT*HID; i += 256){ wa[i]=Wa[i]; wb[i]=Wb[i]; }
  __syncthreads();
  const int j = threadIdx.x & 63, ln = threadIdx.x >> 6;
  const float bb = bias_b[j];
  const int ngroups = (N_NODES+3)/4;
  for (int grp = blockIdx.x; grp < ngroups; grp += gridDim.x){
    int node = grp*4 + ln;
    if (node >= N_NODES) continue;
    float xv0 = X[node*FEAT + j], xv1 = X[node*FEAT + 64 + j];
    float acca = 0.f, accb = bb;
    #pragma unroll 16
    for (int kk = 0; kk < 64; kk++){
      float xb = __shfl(xv0, kk, 64);
      acca += xb * wa[kk*HID + j];
      accb += xb * wb[kk*HID + j];
    }
    #pragma unroll 16
    for (int kk = 0; kk < 64; kk++){
      float xb = __shfl(xv1, kk, 64);
      acca += xb * wa[(64+kk)*HID + j];
      accb += xb * wb[(64+kk)*HID + j];
    }
    outa[node*HID+j] = acca;
    outb[node*HID+j] = accb;
  }
}

// ---------------- CSR build --------------------------------------------------
__global__ __launch_bounds__(256) void k_hist(const int* __restrict__ dst, int* __restrict__ deg)
{
  int e = blockIdx.x*256 + threadIdx.x;
  if (e < N_EDGES) atomicAdd(&deg[dst[e]], 1);
}

__global__ __launch_bounds__(1024) void k_scan(const int* __restrict__ deg,
                                               int* __restrict__ row_start,
                                               int* __restrict__ cursor)
{
  const int SEG = (N_NODES + 1023) / 1024;     // 25
  const int t = threadIdx.x, lane = t & 63, wid = t >> 6;
  int begin = t*SEG, end = begin+SEG; if (end > N_NODES) end = N_NODES;
  if (begin > N_NODES) begin = N_NODES;
  int lsum = 0;
  for (int i = begin; i < end; i++) lsum += deg[i];
  int v = lsum;
  #pragma unroll
  for (int off = 1; off < 64; off <<= 1){
    int u = __shfl_up(v, off, 64);
    if (lane >= off) v += u;
  }
  __shared__ int wsum[16];
  __shared__ int wpre[16];
  if (lane == 63) wsum[wid] = v;
  __syncthreads();
  if (t == 0){
    int run = 0;
    for (int w = 0; w < 16; w++){ wpre[w] = run; run += wsum[w]; }
  }
  __syncthreads();
  int excl = wpre[wid] + v - lsum;
  int run = excl;
  for (int i = begin; i < end; i++){
    row_start[i] = run; cursor[i] = run;
    run += deg[i];
  }
  if (t == 0) row_start[N_NODES] = N_EDGES;
}

__global__ __launch_bounds__(256) void k_fill(const int* __restrict__ src,
                                              const int* __restrict__ dst,
                                              int* __restrict__ cursor,
                                              int* __restrict__ perm_src)
{
  int e = blockIdx.x*256 + threadIdx.x;
  if (e >= N_EDGES) return;
  int pos = atomicAdd(&cursor[dst[e]], 1);
  perm_src[pos] = src[e];
}

// -------- gather aggregation: out = relu(root + sum_in feat[src]), LDS-staged
__global__ __launch_bounds__(256) void k_agg_gather64(
    const int* __restrict__ row_start, const int* __restrict__ perm_src,
    const float* __restrict__ feat, const float* __restrict__ root,
    float* __restrict__ out)
{
  const int nb = blockIdx.x * 4;            // 4 nodes per block (contiguous CSR span)
  const int w = threadIdx.x >> 6, j = threadIdx.x & 63;
  const int node = nb + w;
  const int b0 = row_start[nb];
  const int b1 = row_start[nb+4 < N_NODES ? nb+4 : N_NODES];
  __shared__ int s_lds[512];
  float acc = 0.f; int s0 = 0, s1 = 0;
  if (node < N_NODES){
    s0 = row_start[node]; s1 = row_start[node+1];
    acc = root[node*HID + j];
  }
  for (int base = b0; base < b1; base += 512){
    int cnt = min(512, b1 - base);
    __syncthreads();
    for (int i = threadIdx.x; i < cnt; i += 256) s_lds[i] = perm_src[base + i];
    __syncthreads();
    int lo = max(s0, base), hi = min(s1, base + cnt);
    int e = lo;
    for (; e + 4 <= hi; e += 4){
      int t0=s_lds[e-base], t1=s_lds[e-base+1], t2=s_lds[e-base+2], t3=s_lds[e-base+3];
      float x0=feat[t0*HID+j], x1=feat[t1*HID+j], x2=feat[t2*HID+j], x3=feat[t3*HID+j];
      acc += x0; acc += x1; acc += x2; acc += x3;
    }
    for (; e < hi; e++) acc += feat[s_lds[e-base]*HID + j];
  }
  if (node < N_NODES) out[node*HID + j] = fmaxf(acc, 0.f);
}

// ---------------- GAT: transform + attention logits --------------------------
__global__ __launch_bounds__(256) void k3_gat_transform(
    const float* __restrict__ h1, const float* __restrict__ Wg,
    const float* __restrict__ att_src, const float* __restrict__ att_dst,
    float* __restrict__ xl, float* __restrict__ a_s, float* __restrict__ a_d)
{
  __shared__ float wg[HID*HH];          // exactly 64 KB
  for (int i = threadIdx.x; i < HID*HH; i += 256) wg[i] = Wg[i];
  __syncthreads();
  const int hc = threadIdx.x, h = hc >> 6, c = hc & 63;
  const float asv = att_src[h*HID + c];
  const float adv = att_dst[h*HID + c];
  for (int node = blockIdx.x; node < N_NODES; node += gridDim.x){
    float hval = h1[node*HID + c];
    float acc = 0.f;
    #pragma unroll 16
    for (int k = 0; k < HID; k++){
      float hk = __shfl(hval, k, 64);
      acc += hk * wg[k*HH + hc];
    }
    xl[node*HH + hc] = acc;
    float s1 = acc * asv, s2 = acc * adv;
    #pragma unroll
    for (int off = 32; off > 0; off >>= 1){
      s1 += __shfl_down(s1, off, 64);
      s2 += __shfl_down(s2, off, 64);
    }
    if (c == 0){
      a_s[node*HEADS + h] = s1;
      a_d[node*HEADS + h] = s2;
    }
  }
}

// ---- fused per-node GAT softmax + aggregate (flash-style, exp once per e,h) -
#define GCHUNK 256
__global__ __launch_bounds__(256) void k_gat_node(
    const int* __restrict__ row_start, const int* __restrict__ perm_src,
    const float* __restrict__ xl, const float* __restrict__ a_s,
    const float* __restrict__ a_d, const float* __restrict__ bg,
    float* __restrict__ out)
{
  const int d = blockIdx.x;
  const int hc = threadIdx.x, h = hc >> 6, lane = hc & 63;
  const int s0 = row_start[d], deg = row_start[d+1] - s0;
  __shared__ int   s_lds[GCHUNK];
  __shared__ float p_lds[HEADS][GCHUNK];
  const float ad = a_d[d*HEADS + h];
  const float eself = lrelu(a_s[d*HEADS + h] + ad);
  float m_run = eself;
  float denom = 0.f;
  float acc = 0.f;
  for (int base = 0; base < deg; base += GCHUNK){
    const int cnt = min(GCHUNK, deg - base);
    __syncthreads();                 // protect s_lds across chunks
    for (int i = threadIdx.x; i < cnt; i += 256)
      s_lds[i] = perm_src[s0 + base + i];
    __syncthreads();
    // pass 1: wave h computes its head's logits once per edge (lane-strided)
    float lmax = -1e30f;
    for (int e = lane; e < cnt; e += 64){
      float v = lrelu(a_s[s_lds[e]*HEADS + h] + ad);
      p_lds[h][e] = v;
      lmax = fmaxf(lmax, v);
    }
    #pragma unroll
    for (int off = 32; off; off >>= 1) lmax = fmaxf(lmax, __shfl_xor(lmax, off, 64));
    const float m_new = fmaxf(m_run, lmax);
    const float scale = __expf(m_run - m_new);
    float lsum = 0.f;
    for (int e = lane; e < cnt; e += 64){
      float p = __expf(p_lds[h][e] - m_new);
      p_lds[h][e] = p;
      lsum += p;
    }
    #pragma unroll
    for (int off = 32; off; off >>= 1) lsum += __shfl_xor(lsum, off, 64);
    denom = denom*scale + lsum;
    acc  *= scale;
    m_run = m_new;
    // pass 2: all lanes, 1 fma + 1 broadcast LDS read per edge, unrolled x4
    int e = 0;
    for (; e + 4 <= cnt; e += 4){
      float p0=p_lds[h][e],   p1=p_lds[h][e+1], p2=p_lds[h][e+2], p3=p_lds[h][e+3];
      int   t0=s_lds[e],      t1=s_lds[e+1],    t2=s_lds[e+2],    t3=s_lds[e+3];
      float x0=xl[t0*HH+hc],  x1=xl[t1*HH+hc],  x2=xl[t2*HH+hc],  x3=xl[t3*HH+hc];
      acc += p0*x0; acc += p1*x1; acc += p2*x2; acc += p3*x3;
    }
    for (; e < cnt; e++)
      acc += p_lds[h][e] * xl[s_lds[e]*HH + hc];
  }
  const float pself = __expf(eself - m_run);
  denom += pself;
  acc += pself * xl[d*HH + hc];
  out[d*HH + hc] = fmaxf(acc/denom + bg[hc], 0.f);
}

// ---------------- pool: run-length segment reduce over sorted batch ----------
__global__ __launch_bounds__(256) void k_pool(
    const float* __restrict__ h3, const int* __restrict__ batch,
    float* __restrict__ g)
{
  const int w = blockIdx.x*4 + (threadIdx.x >> 6);   // global wave id
  const int j = threadIdx.x & 63;
  int n0 = w*64;
  if (n0 >= N_NODES) return;
  int n1 = min(n0+64, N_NODES);
  float acc = 0.f;
  int cur = batch[n0];
  for (int n = n0; n < n1; n++){
    int b = batch[n];
    if (b != cur){ atomicAdd(&g[cur*HID + j], acc); acc = 0.f; cur = b; }
    acc += h3[n*HID + j];
  }
  atomicAdd(&g[cur*HID + j], acc);
}

__global__ __launch_bounds__(256) void k_head(
    const float* __restrict__ g, const float* __restrict__ W1,
    const float* __restrict__ b1, const float* __restrict__ W2,
    const float* __restrict__ b2, float* __restrict__ out)
{
  __shared__ float gs[NUM_GRAPHS*HID];
  __shared__ float hh[NUM_GRAPHS*HID];
  for (int i = threadIdx.x; i < NUM_GRAPHS*HID; i += 256) gs[i] = g[i];
  __syncthreads();
  for (int t = threadIdx.x; t < NUM_GRAPHS*HID; t += 256){
    int b = t >> 6, j = t & 63;
    float acc = b1[j];
    for (int k = 0; k < HID; k++) acc += gs[b*HID+k]*W1[k*HID+j];
    hh[t] = fmaxf(acc, 0.f);
  }
  __syncthreads();
  for (int t = threadIdx.x; t < NUM_GRAPHS*2; t += 256){
    int b = t >> 1, c = t & 1;
    float acc = b2[c];
    for (int k = 0; k < HID; k++) acc += hh[b*HID+k]*W2[k*2+c];
    out[t] = 1.f / (1.f + __expf(-acc));
  }
}

extern "C" void kernel_launch(void* const* d_in, const int* in_sizes, int n_in,
                              void* d_out, int out_size, void* d_ws, size_t ws_size,
                              hipStream_t stream)
{
  const float* x       = (const float*)d_in[0];
  const int*   ei      = (const int*)d_in[1];
  const int*   batch   = (const int*)d_in[2];
  const float* W1_rel  = (const float*)d_in[3];
  const float* b1      = (const float*)d_in[4];
  const float* W1_root = (const float*)d_in[5];
  const float* Wg      = (const float*)d_in[6];
  const float* att_src = (const float*)d_in[7];
  const float* att_dst = (const float*)d_in[8];
  const float* bg      = (const float*)d_in[9];
  const float* W5_rel  = (const float*)d_in[10];
  const float* b5      = (const float*)d_in[11];
  const float* W5_root = (const float*)d_in[12];
  const float* W_fc1   = (const float*)d_in[13];
  const float* b_fc1   = (const float*)d_in[14];
  const float* W_fc2   = (const float*)d_in[15];
  const float* b_fc2   = (const float*)d_in[16];
  const int* src = ei;
  const int* dst = ei + N_EDGES;

  float* ws   = (float*)d_ws;
  float* xr   = ws;                     // N*64   (slot A; reused by conv5 rel)
  float* hB   = ws +  1600000;          // N*64   (slot B: hroot -> h1 -> h3)
  float* xl   = ws +  3200000;          // N*256
  float* a_s  = ws +  9600000;          // N*4
  float* a_d  = ws +  9700000;          // N*4
  float* h2   = ws +  9800000;          // N*256
  float* g    = ws + 16200000;          // 64*64
  int*   ib   = (int*)(ws + 16210000);
  int* deg      = ib;                   // 25000
  int* row_st   = ib + 25000;           // 25001 (+pad)
  int* cursor   = ib + 50016;           // 25000
  int* perm_src = ib + 75016;           // 400000
  float* out  = (float*)d_out;

  // CSR build
  hipMemsetAsync(deg, 0, N_NODES*sizeof(int), stream);
  hipMemsetAsync(g, 0, NUM_GRAPHS*HID*sizeof(float), stream);
  k_hist<<<(N_EDGES+255)/256,256,0,stream>>>(dst, deg);
  k_scan<<<1,1024,0,stream>>>(deg, row_st, cursor);
  k_fill<<<(N_EDGES+255)/256,256,0,stream>>>(src, dst, cursor, perm_src);

  // conv1: xr = x@W1_rel ; hB = x@W1_root + b1 (one fused kernel)
  node_gemm_dual128<<<1024,256,0,stream>>>(x, W1_rel, W1_root, b1, xr, hB);
  k_agg_gather64<<<(N_NODES+3)/4,256,0,stream>>>(row_st, perm_src, xr, hB, hB);

  // GAT
  k3_gat_transform<<<1024,256,0,stream>>>(hB, Wg, att_src, att_dst, xl, a_s, a_d);
  k_gat_node<<<N_NODES,256,0,stream>>>(row_st, perm_src, xl, a_s, a_d, bg, h2);

  // conv5
  node_gemm64<HH><<<1024,256,0,stream>>>(h2, W5_rel, nullptr, xr);
  node_gemm64<HH><<<1024,256,0,stream>>>(h2, W5_root, b5, hB);
  k_agg_gather64<<<(N_NODES+3)/4,256,0,stream>>>(row_st, perm_src, xr, hB, hB);

  // pool + head
  k_pool<<<(N_NODES/256)+1,256,0,stream>>>(hB, batch, g);
  k_head<<<1,256,0,stream>>>(g, W_fc1, b_fc1, W_fc2, b_fc2, out);
}

// Round 4
// 441.186 us; speedup vs baseline: 2.5240x; 1.5390x over previous
//
#include <hip/hip_runtime.h>
#include <math.h>

#define N_NODES 25000
#define N_EDGES 400000
#define FEAT 128
#define HID 64
#define HEADS 4
#define HH 256   // HEADS*HID
#define NUM_GRAPHS 64

__device__ __forceinline__ float lrelu(float x){ return x > 0.f ? x : 0.2f*x; }

// ============ conv1: dual GEMM (rel+root), K=128, M=64 =======================
// wave w: matrix m=w>>1, node-subgroup o=w&1. Weights in VGPRs (128/thread),
// activations via wave-uniform scalar loads (s_load + v_fmac sgpr-operand).
__global__ __launch_bounds__(256) void conv1_gemm(
    const float* __restrict__ X, const float* __restrict__ Wrel,
    const float* __restrict__ Wroot, const float* __restrict__ bias,
    float* __restrict__ out_rel, float* __restrict__ out_root)
{
  const int w    = __builtin_amdgcn_readfirstlane(threadIdx.x >> 6);
  const int lane = threadIdx.x & 63;
  const int m = w >> 1, o = w & 1;
  const float* Wm = m ? Wroot : Wrel;
  float wreg[FEAT];
  #pragma unroll
  for (int k = 0; k < FEAT; k++) wreg[k] = Wm[k*HID + lane];
  const float bv = m ? bias[lane] : 0.f;
  float* outp = m ? out_root : out_rel;
  for (int base = blockIdx.x*8; base < N_NODES; base += gridDim.x*8){
    const int n0 = base + o*4;                 // 25000 % 8 == 0 -> no OOB
    const float* __restrict__ xr = X + (size_t)n0*FEAT;
    float acc0=bv, acc1=bv, acc2=bv, acc3=bv;
    #pragma unroll
    for (int k = 0; k < FEAT; k++){
      const float wv = wreg[k];
      acc0 += xr[k]*wv;
      acc1 += xr[FEAT+k]*wv;
      acc2 += xr[2*FEAT+k]*wv;
      acc3 += xr[3*FEAT+k]*wv;
    }
    outp[(size_t)(n0+0)*HID + lane] = acc0;
    outp[(size_t)(n0+1)*HID + lane] = acc1;
    outp[(size_t)(n0+2)*HID + lane] = acc2;
    outp[(size_t)(n0+3)*HID + lane] = acc3;
  }
}

// ============ conv5: dual GEMM, K=256, M=64 ==================================
// wave w: matrix m=w>>1, K-chunk q=w&1 (128 each). All waves share 4 nodes;
// partials combined through 4KB LDS.
__global__ __launch_bounds__(256) void conv5_gemm(
    const float* __restrict__ X, const float* __restrict__ Wrel,
    const float* __restrict__ Wroot, const float* __restrict__ bias,
    float* __restrict__ out_rel, float* __restrict__ out_root)
{
  const int w    = __builtin_amdgcn_readfirstlane(threadIdx.x >> 6);
  const int lane = threadIdx.x & 63;
  const int m = w >> 1, q = w & 1;
  const float* Wm = (m ? Wroot : Wrel) + (size_t)q*128*HID;
  float wreg[128];
  #pragma unroll
  for (int k = 0; k < 128; k++) wreg[k] = Wm[k*HID + lane];
  __shared__ float part[2][2][4][64];
  for (int base = blockIdx.x*4; base < N_NODES; base += gridDim.x*4){
    const float* __restrict__ xr = X + (size_t)base*HH + q*128;
    float acc0=0, acc1=0, acc2=0, acc3=0;
    #pragma unroll
    for (int k = 0; k < 128; k++){
      const float wv = wreg[k];
      acc0 += xr[k]*wv;
      acc1 += xr[HH+k]*wv;
      acc2 += xr[2*HH+k]*wv;
      acc3 += xr[3*HH+k]*wv;
    }
    __syncthreads();
    part[m][q][0][lane]=acc0; part[m][q][1][lane]=acc1;
    part[m][q][2][lane]=acc2; part[m][q][3][lane]=acc3;
    __syncthreads();
    #pragma unroll
    for (int t = threadIdx.x; t < 512; t += 256){
      int mm = t >> 8, ii = (t >> 6) & 3, cc = t & 63;
      float v = part[mm][0][ii][cc] + part[mm][1][ii][cc];
      if (mm) v += bias[cc];
      (mm ? out_root : out_rel)[(size_t)(base+ii)*HID + cc] = v;
    }
  }
}

// ============ GAT transform: xl = h1@Wg (K=64, M=256) + head dots ============
__global__ __launch_bounds__(256) void k3_gat_transform(
    const float* __restrict__ h1, const float* __restrict__ Wg,
    const float* __restrict__ att_src, const float* __restrict__ att_dst,
    float* __restrict__ xl, float* __restrict__ a_s, float* __restrict__ a_d)
{
  const int hc = threadIdx.x, h = hc >> 6, lane = hc & 63;
  float wreg[HID];
  #pragma unroll
  for (int k = 0; k < HID; k++) wreg[k] = Wg[k*HH + hc];
  const float asv = att_src[h*HID + lane];
  const float adv = att_dst[h*HID + lane];
  for (int base = blockIdx.x*4; base < N_NODES; base += gridDim.x*4){
    const float* __restrict__ xr = h1 + (size_t)base*HID;
    float acc0=0, acc1=0, acc2=0, acc3=0;
    #pragma unroll
    for (int k = 0; k < HID; k++){
      const float wv = wreg[k];
      acc0 += xr[k]*wv;
      acc1 += xr[HID+k]*wv;
      acc2 += xr[2*HID+k]*wv;
      acc3 += xr[3*HID+k]*wv;
    }
    float accs[4] = {acc0, acc1, acc2, acc3};
    #pragma unroll
    for (int i = 0; i < 4; i++){
      xl[(size_t)(base+i)*HH + hc] = accs[i];
      float s1 = accs[i]*asv, s2 = accs[i]*adv;
      #pragma unroll
      for (int off = 32; off; off >>= 1){
        s1 += __shfl_xor(s1, off, 64);
        s2 += __shfl_xor(s2, off, 64);
      }
      if (lane == 0){
        a_s[(base+i)*HEADS + h] = s1;
        a_d[(base+i)*HEADS + h] = s2;
      }
    }
  }
}

// ---------------- CSR build --------------------------------------------------
__global__ __launch_bounds__(256) void k_hist(const int* __restrict__ dst, int* __restrict__ deg)
{
  int e = blockIdx.x*256 + threadIdx.x;
  if (e < N_EDGES) atomicAdd(&deg[dst[e]], 1);
}

__global__ __launch_bounds__(1024) void k_scan(const int* __restrict__ deg,
                                               int* __restrict__ row_start,
                                               int* __restrict__ cursor)
{
  const int SEG = (N_NODES + 1023) / 1024;     // 25
  const int t = threadIdx.x, lane = t & 63, wid = t >> 6;
  int begin = t*SEG, end = begin+SEG; if (end > N_NODES) end = N_NODES;
  if (begin > N_NODES) begin = N_NODES;
  int lsum = 0;
  for (int i = begin; i < end; i++) lsum += deg[i];
  int v = lsum;
  #pragma unroll
  for (int off = 1; off < 64; off <<= 1){
    int u = __shfl_up(v, off, 64);
    if (lane >= off) v += u;
  }
  __shared__ int wsum[16];
  __shared__ int wpre[16];
  if (lane == 63) wsum[wid] = v;
  __syncthreads();
  if (t == 0){
    int run = 0;
    for (int w = 0; w < 16; w++){ wpre[w] = run; run += wsum[w]; }
  }
  __syncthreads();
  int excl = wpre[wid] + v - lsum;
  int run = excl;
  for (int i = begin; i < end; i++){
    row_start[i] = run; cursor[i] = run;
    run += deg[i];
  }
  if (t == 0) row_start[N_NODES] = N_EDGES;
}

__global__ __launch_bounds__(256) void k_fill(const int* __restrict__ src,
                                              const int* __restrict__ dst,
                                              int* __restrict__ cursor,
                                              int* __restrict__ perm_src)
{
  int e = blockIdx.x*256 + threadIdx.x;
  if (e >= N_EDGES) return;
  int pos = atomicAdd(&cursor[dst[e]], 1);
  perm_src[pos] = src[e];
}

// -------- gather aggregation: out = relu(root + sum_in feat[src]), LDS-staged
__global__ __launch_bounds__(256) void k_agg_gather64(
    const int* __restrict__ row_start, const int* __restrict__ perm_src,
    const float* __restrict__ feat, const float* __restrict__ root,
    float* __restrict__ out)
{
  const int nb = blockIdx.x * 4;
  const int w = threadIdx.x >> 6, j = threadIdx.x & 63;
  const int node = nb + w;
  const int b0 = row_start[nb];
  const int b1 = row_start[nb+4 < N_NODES ? nb+4 : N_NODES];
  __shared__ int s_lds[512];
  float acc = 0.f; int s0 = 0, s1 = 0;
  if (node < N_NODES){
    s0 = row_start[node]; s1 = row_start[node+1];
    acc = root[node*HID + j];
  }
  for (int base = b0; base < b1; base += 512){
    int cnt = min(512, b1 - base);
    __syncthreads();
    for (int i = threadIdx.x; i < cnt; i += 256) s_lds[i] = perm_src[base + i];
    __syncthreads();
    int lo = max(s0, base), hi = min(s1, base + cnt);
    int e = lo;
    for (; e + 4 <= hi; e += 4){
      int t0=s_lds[e-base], t1=s_lds[e-base+1], t2=s_lds[e-base+2], t3=s_lds[e-base+3];
      float x0=feat[t0*HID+j], x1=feat[t1*HID+j], x2=feat[t2*HID+j], x3=feat[t3*HID+j];
      acc += x0; acc += x1; acc += x2; acc += x3;
    }
    for (; e < hi; e++) acc += feat[s_lds[e-base]*HID + j];
  }
  if (node < N_NODES) out[node*HID + j] = fmaxf(acc, 0.f);
}

// ---- fused per-node GAT softmax + aggregate (flash-style) -------------------
#define GCHUNK 256
__global__ __launch_bounds__(256) void k_gat_node(
    const int* __restrict__ row_start, const int* __restrict__ perm_src,
    const float* __restrict__ xl, const float* __restrict__ a_s,
    const float* __restrict__ a_d, const float* __restrict__ bg,
    float* __restrict__ out)
{
  const int d = blockIdx.x;
  const int hc = threadIdx.x, h = hc >> 6, lane = hc & 63;
  const int s0 = row_start[d], deg = row_start[d+1] - s0;
  __shared__ int   s_lds[GCHUNK];
  __shared__ float p_lds[HEADS][GCHUNK];
  const float ad = a_d[d*HEADS + h];
  const float eself = lrelu(a_s[d*HEADS + h] + ad);
  float m_run = eself;
  float denom = 0.f;
  float acc = 0.f;
  for (int base = 0; base < deg; base += GCHUNK){
    const int cnt = min(GCHUNK, deg - base);
    __syncthreads();
    for (int i = threadIdx.x; i < cnt; i += 256)
      s_lds[i] = perm_src[s0 + base + i];
    __syncthreads();
    float lmax = -1e30f;
    for (int e = lane; e < cnt; e += 64){
      float v = lrelu(a_s[s_lds[e]*HEADS + h] + ad);
      p_lds[h][e] = v;
      lmax = fmaxf(lmax, v);
    }
    #pragma unroll
    for (int off = 32; off; off >>= 1) lmax = fmaxf(lmax, __shfl_xor(lmax, off, 64));
    const float m_new = fmaxf(m_run, lmax);
    const float scale = __expf(m_run - m_new);
    float lsum = 0.f;
    for (int e = lane; e < cnt; e += 64){
      float p = __expf(p_lds[h][e] - m_new);
      p_lds[h][e] = p;
      lsum += p;
    }
    #pragma unroll
    for (int off = 32; off; off >>= 1) lsum += __shfl_xor(lsum, off, 64);
    denom = denom*scale + lsum;
    acc  *= scale;
    m_run = m_new;
    int e = 0;
    for (; e + 4 <= cnt; e += 4){
      float p0=p_lds[h][e],   p1=p_lds[h][e+1], p2=p_lds[h][e+2], p3=p_lds[h][e+3];
      int   t0=s_lds[e],      t1=s_lds[e+1],    t2=s_lds[e+2],    t3=s_lds[e+3];
      float x0=xl[t0*HH+hc],  x1=xl[t1*HH+hc],  x2=xl[t2*HH+hc],  x3=xl[t3*HH+hc];
      acc += p0*x0; acc += p1*x1; acc += p2*x2; acc += p3*x3;
    }
    for (; e < cnt; e++)
      acc += p_lds[h][e] * xl[s_lds[e]*HH + hc];
  }
  const float pself = __expf(eself - m_run);
  denom += pself;
  acc += pself * xl[d*HH + hc];
  out[d*HH + hc] = fmaxf(acc/denom + bg[hc], 0.f);
}

// ---------------- pool: run-length segment reduce over sorted batch ----------
__global__ __launch_bounds__(256) void k_pool(
    const float* __restrict__ h3, const int* __restrict__ batch,
    float* __restrict__ g)
{
  const int w = blockIdx.x*4 + (threadIdx.x >> 6);
  const int j = threadIdx.x & 63;
  int n0 = w*64;
  if (n0 >= N_NODES) return;
  int n1 = min(n0+64, N_NODES);
  float acc = 0.f;
  int cur = batch[n0];
  for (int n = n0; n < n1; n++){
    int b = batch[n];
    if (b != cur){ atomicAdd(&g[cur*HID + j], acc); acc = 0.f; cur = b; }
    acc += h3[n*HID + j];
  }
  atomicAdd(&g[cur*HID + j], acc);
}

__global__ __launch_bounds__(256) void k_head(
    const float* __restrict__ g, const float* __restrict__ W1,
    const float* __restrict__ b1, const float* __restrict__ W2,
    const float* __restrict__ b2, float* __restrict__ out)
{
  __shared__ float gs[NUM_GRAPHS*HID];
  __shared__ float hh[NUM_GRAPHS*HID];
  for (int i = threadIdx.x; i < NUM_GRAPHS*HID; i += 256) gs[i] = g[i];
  __syncthreads();
  for (int t = threadIdx.x; t < NUM_GRAPHS*HID; t += 256){
    int b = t >> 6, j = t & 63;
    float acc = b1[j];
    for (int k = 0; k < HID; k++) acc += gs[b*HID+k]*W1[k*HID+j];
    hh[t] = fmaxf(acc, 0.f);
  }
  __syncthreads();
  for (int t = threadIdx.x; t < NUM_GRAPHS*2; t += 256){
    int b = t >> 1, c = t & 1;
    float acc = b2[c];
    for (int k = 0; k < HID; k++) acc += hh[b*HID+k]*W2[k*2+c];
    out[t] = 1.f / (1.f + __expf(-acc));
  }
}

extern "C" void kernel_launch(void* const* d_in, const int* in_sizes, int n_in,
                              void* d_out, int out_size, void* d_ws, size_t ws_size,
                              hipStream_t stream)
{
  const float* x       = (const float*)d_in[0];
  const int*   ei      = (const int*)d_in[1];
  const int*   batch   = (const int*)d_in[2];
  const float* W1_rel  = (const float*)d_in[3];
  const float* b1      = (const float*)d_in[4];
  const float* W1_root = (const float*)d_in[5];
  const float* Wg      = (const float*)d_in[6];
  const float* att_src = (const float*)d_in[7];
  const float* att_dst = (const float*)d_in[8];
  const float* bg      = (const float*)d_in[9];
  const float* W5_rel  = (const float*)d_in[10];
  const float* b5      = (const float*)d_in[11];
  const float* W5_root = (const float*)d_in[12];
  const float* W_fc1   = (const float*)d_in[13];
  const float* b_fc1   = (const float*)d_in[14];
  const float* W_fc2   = (const float*)d_in[15];
  const float* b_fc2   = (const float*)d_in[16];
  const int* src = ei;
  const int* dst = ei + N_EDGES;

  float* ws   = (float*)d_ws;
  float* xr   = ws;                     // N*64   (slot A; reused by conv5 rel)
  float* hB   = ws +  1600000;          // N*64   (slot B: hroot -> h1 -> h3)
  float* xl   = ws +  3200000;          // N*256
  float* a_s  = ws +  9600000;          // N*4
  float* a_d  = ws +  9700000;          // N*4
  float* h2   = ws +  9800000;          // N*256
  float* g    = ws + 16200000;          // 64*64
  int*   ib   = (int*)(ws + 16210000);
  int* deg      = ib;                   // 25000
  int* row_st   = ib + 25000;           // 25001 (+pad)
  int* cursor   = ib + 50016;           // 25000
  int* perm_src = ib + 75016;           // 400000
  float* out  = (float*)d_out;

  // CSR build
  hipMemsetAsync(deg, 0, N_NODES*sizeof(int), stream);
  hipMemsetAsync(g, 0, NUM_GRAPHS*HID*sizeof(float), stream);
  k_hist<<<(N_EDGES+255)/256,256,0,stream>>>(dst, deg);
  k_scan<<<1,1024,0,stream>>>(deg, row_st, cursor);
  k_fill<<<(N_EDGES+255)/256,256,0,stream>>>(src, dst, cursor, perm_src);

  // conv1
  conv1_gemm<<<1024,256,0,stream>>>(x, W1_rel, W1_root, b1, xr, hB);
  k_agg_gather64<<<(N_NODES+3)/4,256,0,stream>>>(row_st, perm_src, xr, hB, hB);

  // GAT
  k3_gat_transform<<<1024,256,0,stream>>>(hB, Wg, att_src, att_dst, xl, a_s, a_d);
  k_gat_node<<<N_NODES,256,0,stream>>>(row_st, perm_src, xl, a_s, a_d, bg, h2);

  // conv5
  conv5_gemm<<<1024,256,0,stream>>>(h2, W5_rel, W5_root, b5, xr, hB);
  k_agg_gather64<<<(N_NODES+3)/4,256,0,stream>>>(row_st, perm_src, xr, hB, hB);

  // pool + head
  k_pool<<<(N_NODES/256)+1,256,0,stream>>>(hB, batch, g);
  k_head<<<1,256,0,stream>>>(g, W_fc1, b_fc1, W_fc2, b_fc2, out);
}

// Round 5
// 436.305 us; speedup vs baseline: 2.5523x; 1.0112x over previous
//
#include <hip/hip_runtime.h>
#include <math.h>

#define N_NODES 25000
#define N_EDGES 400000
#define FEAT 128
#define HID 64
#define HEADS 4
#define HH 256   // HEADS*HID
#define NUM_GRAPHS 64

__device__ __forceinline__ float lrelu(float x){ return x > 0.f ? x : 0.2f*x; }

// ============ conv1: dual GEMM (rel+root), K=128, M=64 =======================
__global__ __launch_bounds__(256) void conv1_gemm(
    const float* __restrict__ X, const float* __restrict__ Wrel,
    const float* __restrict__ Wroot, const float* __restrict__ bias,
    float* __restrict__ out_rel, float* __restrict__ out_root)
{
  const int w    = __builtin_amdgcn_readfirstlane(threadIdx.x >> 6);
  const int lane = threadIdx.x & 63;
  const int m = w >> 1, o = w & 1;
  const float* Wm = m ? Wroot : Wrel;
  float wreg[FEAT];
  #pragma unroll
  for (int k = 0; k < FEAT; k++) wreg[k] = Wm[k*HID + lane];
  const float bv = m ? bias[lane] : 0.f;
  float* outp = m ? out_root : out_rel;
  for (int base = blockIdx.x*8; base < N_NODES; base += gridDim.x*8){
    const int n0 = base + o*4;                 // 25000 % 8 == 0 -> no OOB
    const float* __restrict__ xr = X + (size_t)n0*FEAT;
    float acc0=bv, acc1=bv, acc2=bv, acc3=bv;
    #pragma unroll
    for (int k = 0; k < FEAT; k++){
      const float wv = wreg[k];
      acc0 += xr[k]*wv;
      acc1 += xr[FEAT+k]*wv;
      acc2 += xr[2*FEAT+k]*wv;
      acc3 += xr[3*FEAT+k]*wv;
    }
    outp[(size_t)(n0+0)*HID + lane] = acc0;
    outp[(size_t)(n0+1)*HID + lane] = acc1;
    outp[(size_t)(n0+2)*HID + lane] = acc2;
    outp[(size_t)(n0+3)*HID + lane] = acc3;
  }
}

// ============ conv5: dual GEMM, K=256 (split-K), M=64 ========================
__global__ __launch_bounds__(256) void conv5_gemm(
    const float* __restrict__ X, const float* __restrict__ Wrel,
    const float* __restrict__ Wroot, const float* __restrict__ bias,
    float* __restrict__ out_rel, float* __restrict__ out_root)
{
  const int w    = __builtin_amdgcn_readfirstlane(threadIdx.x >> 6);
  const int lane = threadIdx.x & 63;
  const int m = w >> 1, q = w & 1;
  const float* Wm = (m ? Wroot : Wrel) + (size_t)q*128*HID;
  float wreg[128];
  #pragma unroll
  for (int k = 0; k < 128; k++) wreg[k] = Wm[k*HID + lane];
  __shared__ float part[2][2][4][64];
  for (int base = blockIdx.x*4; base < N_NODES; base += gridDim.x*4){
    const float* __restrict__ xr = X + (size_t)base*HH + q*128;
    float acc0=0, acc1=0, acc2=0, acc3=0;
    #pragma unroll
    for (int k = 0; k < 128; k++){
      const float wv = wreg[k];
      acc0 += xr[k]*wv;
      acc1 += xr[HH+k]*wv;
      acc2 += xr[2*HH+k]*wv;
      acc3 += xr[3*HH+k]*wv;
    }
    __syncthreads();
    part[m][q][0][lane]=acc0; part[m][q][1][lane]=acc1;
    part[m][q][2][lane]=acc2; part[m][q][3][lane]=acc3;
    __syncthreads();
    #pragma unroll
    for (int t = threadIdx.x; t < 512; t += 256){
      int mm = t >> 8, ii = (t >> 6) & 3, cc = t & 63;
      float v = part[mm][0][ii][cc] + part[mm][1][ii][cc];
      if (mm) v += bias[cc];
      (mm ? out_root : out_rel)[(size_t)(base+ii)*HID + cc] = v;
    }
  }
}

// ============ GAT transform: xl = h1@Wg (K=64, M=256) + head dots ============
__global__ __launch_bounds__(256) void k3_gat_transform(
    const float* __restrict__ h1, const float* __restrict__ Wg,
    const float* __restrict__ att_src, const float* __restrict__ att_dst,
    float* __restrict__ xl, float* __restrict__ a_s, float* __restrict__ a_d)
{
  const int hc = threadIdx.x, h = hc >> 6, lane = hc & 63;
  float wreg[HID];
  #pragma unroll
  for (int k = 0; k < HID; k++) wreg[k] = Wg[k*HH + hc];
  const float asv = att_src[h*HID + lane];
  const float adv = att_dst[h*HID + lane];
  for (int base = blockIdx.x*4; base < N_NODES; base += gridDim.x*4){
    const float* __restrict__ xr = h1 + (size_t)base*HID;
    float acc0=0, acc1=0, acc2=0, acc3=0;
    #pragma unroll
    for (int k = 0; k < HID; k++){
      const float wv = wreg[k];
      acc0 += xr[k]*wv;
      acc1 += xr[HID+k]*wv;
      acc2 += xr[2*HID+k]*wv;
      acc3 += xr[3*HID+k]*wv;
    }
    float accs[4] = {acc0, acc1, acc2, acc3};
    #pragma unroll
    for (int i = 0; i < 4; i++){
      xl[(size_t)(base+i)*HH + hc] = accs[i];
      float s1 = accs[i]*asv, s2 = accs[i]*adv;
      #pragma unroll
      for (int off = 32; off; off >>= 1){
        s1 += __shfl_xor(s1, off, 64);
        s2 += __shfl_xor(s2, off, 64);
      }
      if (lane == 0){
        a_s[(base+i)*HEADS + h] = s1;
        a_d[(base+i)*HEADS + h] = s2;
      }
    }
  }
}

// ---------------- CSR build --------------------------------------------------
__global__ __launch_bounds__(256) void k_hist(const int* __restrict__ dst, int* __restrict__ deg)
{
  int e = blockIdx.x*256 + threadIdx.x;
  if (e < N_EDGES) atomicAdd(&deg[dst[e]], 1);
}

__global__ __launch_bounds__(1024) void k_scan(const int* __restrict__ deg,
                                               int* __restrict__ row_start,
                                               int* __restrict__ cursor)
{
  const int SEG = (N_NODES + 1023) / 1024;     // 25
  const int t = threadIdx.x, lane = t & 63, wid = t >> 6;
  int begin = t*SEG, end = begin+SEG; if (end > N_NODES) end = N_NODES;
  if (begin > N_NODES) begin = N_NODES;
  int lsum = 0;
  for (int i = begin; i < end; i++) lsum += deg[i];
  int v = lsum;
  #pragma unroll
  for (int off = 1; off < 64; off <<= 1){
    int u = __shfl_up(v, off, 64);
    if (lane >= off) v += u;
  }
  __shared__ int wsum[16];
  __shared__ int wpre[16];
  if (lane == 63) wsum[wid] = v;
  __syncthreads();
  if (t == 0){
    int run = 0;
    for (int w = 0; w < 16; w++){ wpre[w] = run; run += wsum[w]; }
  }
  __syncthreads();
  int excl = wpre[wid] + v - lsum;
  int run = excl;
  for (int i = begin; i < end; i++){
    row_start[i] = run; cursor[i] = run;
    run += deg[i];
  }
  if (t == 0) row_start[N_NODES] = N_EDGES;
}

__global__ __launch_bounds__(256) void k_fill(const int* __restrict__ src,
                                              const int* __restrict__ dst,
                                              int* __restrict__ cursor,
                                              int* __restrict__ perm_src)
{
  int e = blockIdx.x*256 + threadIdx.x;
  if (e >= N_EDGES) return;
  int pos = atomicAdd(&cursor[dst[e]], 1);
  perm_src[pos] = src[e];
}

// -------- gather agg (float4): out = relu(root + sum_in feat[src]) -----------
// wave per node; 16 lanes x float4 cover the 64-col row; 4 edges in flight.
__global__ __launch_bounds__(256) void k_agg4(
    const int* __restrict__ row_start, const int* __restrict__ perm_src,
    const float4* __restrict__ feat4, const float4* __restrict__ root4,
    float4* __restrict__ out4)
{
  const int node = blockIdx.x*4 + (threadIdx.x >> 6);
  if (node >= N_NODES) return;
  const int lane = threadIdx.x & 63;
  const int eg = lane >> 4, cl = lane & 15;
  const int s0 = row_start[node], s1 = row_start[node+1];
  float ax=0.f, ay=0.f, az=0.f, aw=0.f;
  int base = s0;
  for (; base + 8 <= s1; base += 8){
    int sA = perm_src[base + eg];
    int sB = perm_src[base + 4 + eg];
    float4 a = feat4[(size_t)sA*16 + cl];
    float4 b = feat4[(size_t)sB*16 + cl];
    ax += a.x; ay += a.y; az += a.z; aw += a.w;
    ax += b.x; ay += b.y; az += b.z; aw += b.w;
  }
  for (; base < s1; base += 4){
    int ee = base + eg;
    if (ee < s1){
      int s = perm_src[ee];
      float4 a = feat4[(size_t)s*16 + cl];
      ax += a.x; ay += a.y; az += a.z; aw += a.w;
    }
  }
  #pragma unroll
  for (int off = 16; off <= 32; off <<= 1){
    ax += __shfl_xor(ax, off, 64);
    ay += __shfl_xor(ay, off, 64);
    az += __shfl_xor(az, off, 64);
    aw += __shfl_xor(aw, off, 64);
  }
  if (eg == 0){
    float4 r = root4[(size_t)node*16 + cl];
    float4 o;
    o.x = fmaxf(ax + r.x, 0.f);
    o.y = fmaxf(ay + r.y, 0.f);
    o.z = fmaxf(az + r.z, 0.f);
    o.w = fmaxf(aw + r.w, 0.f);
    out4[(size_t)node*16 + cl] = o;
  }
}

// ---- fused per-node GAT softmax + aggregate (no segment max; float4 fma) ----
#define GCHUNK 256
__global__ __launch_bounds__(256) void k_gat_node(
    const int* __restrict__ row_start, const int* __restrict__ perm_src,
    const float4* __restrict__ xl4, const float* __restrict__ a_s,
    const float* __restrict__ a_d, const float4* __restrict__ bg4,
    float4* __restrict__ out4)
{
  const int d = blockIdx.x;
  const int tid = threadIdx.x, h = tid >> 6, lane = tid & 63;
  const int eg = lane >> 4, cl = lane & 15;
  const int s0 = row_start[d], deg = row_start[d+1] - s0;
  __shared__ int   s_lds[GCHUNK];
  __shared__ float p_lds[HEADS][GCHUNK];
  const float ad = a_d[d*HEADS + h];
  float denom = 0.f;
  float ax=0.f, ay=0.f, az=0.f, aw=0.f;
  for (int base = 0; base < deg; base += GCHUNK){
    const int cnt  = min(GCHUNK, deg - base);
    const int cntp = (cnt + 7) & ~7;
    __syncthreads();
    for (int i = tid; i < cntp; i += 256)
      s_lds[i] = (i < cnt) ? perm_src[s0 + base + i] : d;
    __syncthreads();
    // logits+exp once per (edge,head); lane-strided; pads get p=0
    float lsum = 0.f;
    for (int e = lane; e < cntp; e += 64){
      float p = 0.f;
      if (e < cnt){
        int s = s_lds[e];
        p = __expf(lrelu(a_s[s*HEADS + h] + ad));
      }
      p_lds[h][e] = p;
      lsum += p;
    }
    #pragma unroll
    for (int off = 32; off; off >>= 1) lsum += __shfl_xor(lsum, off, 64);
    denom += lsum;
    // fma pass: 16 lanes x float4 per edge, 4 edges per step, unroll x2
    for (int e0 = 0; e0 < cntp; e0 += 8){
      int eA = e0 + eg, eB = e0 + 4 + eg;
      int sA = s_lds[eA], sB = s_lds[eB];
      float pA = p_lds[h][eA], pB = p_lds[h][eB];
      float4 a = xl4[(size_t)sA*64 + h*16 + cl];
      float4 b = xl4[(size_t)sB*64 + h*16 + cl];
      ax += pA*a.x; ay += pA*a.y; az += pA*a.z; aw += pA*a.w;
      ax += pB*b.x; ay += pB*b.y; az += pB*b.z; aw += pB*b.w;
    }
  }
  #pragma unroll
  for (int off = 16; off <= 32; off <<= 1){
    ax += __shfl_xor(ax, off, 64);
    ay += __shfl_xor(ay, off, 64);
    az += __shfl_xor(az, off, 64);
    aw += __shfl_xor(aw, off, 64);
  }
  // self loop
  const float pself = __expf(lrelu(a_s[d*HEADS + h] + ad));
  denom += pself;
  float4 sv = xl4[(size_t)d*64 + h*16 + cl];
  ax += pself*sv.x; ay += pself*sv.y; az += pself*sv.z; aw += pself*sv.w;
  if (eg == 0){
    const float inv = 1.f / denom;
    float4 bgv = bg4[h*16 + cl];
    float4 o;
    o.x = fmaxf(ax*inv + bgv.x, 0.f);
    o.y = fmaxf(ay*inv + bgv.y, 0.f);
    o.z = fmaxf(az*inv + bgv.z, 0.f);
    o.w = fmaxf(aw*inv + bgv.w, 0.f);
    out4[(size_t)d*64 + h*16 + cl] = o;
  }
}

// ---------------- pool: run-length segment reduce over sorted batch ----------
__global__ __launch_bounds__(256) void k_pool(
    const float* __restrict__ h3, const int* __restrict__ batch,
    float* __restrict__ g)
{
  const int w = blockIdx.x*4 + (threadIdx.x >> 6);
  const int j = threadIdx.x & 63;
  int n0 = w*64;
  if (n0 >= N_NODES) return;
  int n1 = min(n0+64, N_NODES);
  float acc = 0.f;
  int cur = batch[n0];
  for (int n = n0; n < n1; n++){
    int b = batch[n];
    if (b != cur){ atomicAdd(&g[cur*HID + j], acc); acc = 0.f; cur = b; }
    acc += h3[n*HID + j];
  }
  atomicAdd(&g[cur*HID + j], acc);
}

__global__ __launch_bounds__(256) void k_head(
    const float* __restrict__ g, const float* __restrict__ W1,
    const float* __restrict__ b1, const float* __restrict__ W2,
    const float* __restrict__ b2, float* __restrict__ out)
{
  __shared__ float gs[NUM_GRAPHS*HID];
  __shared__ float hh[NUM_GRAPHS*HID];
  for (int i = threadIdx.x; i < NUM_GRAPHS*HID; i += 256) gs[i] = g[i];
  __syncthreads();
  for (int t = threadIdx.x; t < NUM_GRAPHS*HID; t += 256){
    int b = t >> 6, j = t & 63;
    float acc = b1[j];
    for (int k = 0; k < HID; k++) acc += gs[b*HID+k]*W1[k*HID+j];
    hh[t] = fmaxf(acc, 0.f);
  }
  __syncthreads();
  for (int t = threadIdx.x; t < NUM_GRAPHS*2; t += 256){
    int b = t >> 1, c = t & 1;
    float acc = b2[c];
    for (int k = 0; k < HID; k++) acc += hh[b*HID+k]*W2[k*2+c];
    out[t] = 1.f / (1.f + __expf(-acc));
  }
}

extern "C" void kernel_launch(void* const* d_in, const int* in_sizes, int n_in,
                              void* d_out, int out_size, void* d_ws, size_t ws_size,
                              hipStream_t stream)
{
  const float* x       = (const float*)d_in[0];
  const int*   ei      = (const int*)d_in[1];
  const int*   batch   = (const int*)d_in[2];
  const float* W1_rel  = (const float*)d_in[3];
  const float* b1      = (const float*)d_in[4];
  const float* W1_root = (const float*)d_in[5];
  const float* Wg      = (const float*)d_in[6];
  const float* att_src = (const float*)d_in[7];
  const float* att_dst = (const float*)d_in[8];
  const float* bg      = (const float*)d_in[9];
  const float* W5_rel  = (const float*)d_in[10];
  const float* b5      = (const float*)d_in[11];
  const float* W5_root = (const float*)d_in[12];
  const float* W_fc1   = (const float*)d_in[13];
  const float* b_fc1   = (const float*)d_in[14];
  const float* W_fc2   = (const float*)d_in[15];
  const float* b_fc2   = (const float*)d_in[16];
  const int* src = ei;
  const int* dst = ei + N_EDGES;

  float* ws   = (float*)d_ws;
  float* xr   = ws;                     // N*64   (slot A; reused by conv5 rel)
  float* hB   = ws +  1600000;          // N*64   (slot B: hroot -> h1 -> h3)
  float* xl   = ws +  3200000;          // N*256
  float* a_s  = ws +  9600000;          // N*4
  float* a_d  = ws +  9700000;          // N*4
  float* h2   = ws +  9800000;          // N*256
  float* g    = ws + 16200000;          // 64*64 = 4096 floats
  int*   ib   = (int*)(ws + 16204096);  // deg adjacent to g -> single memset
  int* deg      = ib;                   // 25000
  int* row_st   = ib + 25000;           // 25001 (+pad)
  int* cursor   = ib + 50016;           // 25000
  int* perm_src = ib + 75016;           // 400000
  float* out  = (float*)d_out;

  // CSR build (+ zero g in the same memset)
  hipMemsetAsync(g, 0, (4096 + N_NODES)*sizeof(float), stream);
  k_hist<<<(N_EDGES+255)/256,256,0,stream>>>(dst, deg);
  k_scan<<<1,1024,0,stream>>>(deg, row_st, cursor);
  k_fill<<<(N_EDGES+255)/256,256,0,stream>>>(src, dst, cursor, perm_src);

  // conv1
  conv1_gemm<<<1024,256,0,stream>>>(x, W1_rel, W1_root, b1, xr, hB);
  k_agg4<<<(N_NODES+3)/4,256,0,stream>>>(row_st, perm_src,
      (const float4*)xr, (const float4*)hB, (float4*)hB);

  // GAT
  k3_gat_transform<<<1024,256,0,stream>>>(hB, Wg, att_src, att_dst, xl, a_s, a_d);
  k_gat_node<<<N_NODES,256,0,stream>>>(row_st, perm_src,
      (const float4*)xl, a_s, a_d, (const float4*)bg, (float4*)h2);

  // conv5
  conv5_gemm<<<1024,256,0,stream>>>(h2, W5_rel, W5_root, b5, xr, hB);
  k_agg4<<<(N_NODES+3)/4,256,0,stream>>>(row_st, perm_src,
      (const float4*)xr, (const float4*)hB, (float4*)hB);

  // pool + head
  k_pool<<<(N_NODES/256)+1,256,0,stream>>>(hB, batch, g);
  k_head<<<1,256,0,stream>>>(g, W_fc1, b_fc1, W_fc2, b_fc2, out);
}

// Round 7
// 408.895 us; speedup vs baseline: 2.7234x; 1.0670x over previous
//
#include <hip/hip_runtime.h>
#include <math.h>

#define N_NODES 25000
#define N_EDGES 400000
#define FEAT 128
#define HID 64
#define HEADS 4
#define HH 256   // HEADS*HID
#define NUM_GRAPHS 64

typedef unsigned short ushort_t;
typedef unsigned int uint_t;

__device__ __forceinline__ float lrelu(float x){ return x > 0.f ? x : 0.2f*x; }

// fp32 -> bf16 with round-to-nearest-even
__device__ __forceinline__ ushort_t f2bf(float f){
  uint_t u = __float_as_uint(f);
  return (ushort_t)((u + 0x7fffu + ((u >> 16) & 1u)) >> 16);
}
#define BF_LO(u) __uint_as_float((u) << 16)
#define BF_HI(u) __uint_as_float((u) & 0xffff0000u)

// ============ conv1: dual GEMM (rel+root), K=128, M=64; rel out in bf16 ======
__global__ __launch_bounds__(256) void conv1_gemm(
    const float* __restrict__ X, const float* __restrict__ Wrel,
    const float* __restrict__ Wroot, const float* __restrict__ bias,
    ushort_t* __restrict__ out_rel_b, float* __restrict__ out_root)
{
  const int w    = __builtin_amdgcn_readfirstlane(threadIdx.x >> 6);
  const int lane = threadIdx.x & 63;
  const int m = w >> 1, o = w & 1;
  const float* Wm = m ? Wroot : Wrel;
  float wreg[FEAT];
  #pragma unroll
  for (int k = 0; k < FEAT; k++) wreg[k] = Wm[k*HID + lane];
  const float bv = m ? bias[lane] : 0.f;
  for (int base = blockIdx.x*8; base < N_NODES; base += gridDim.x*8){
    const int n0 = base + o*4;                 // 25000 % 8 == 0 -> no OOB
    const float* __restrict__ xr = X + (size_t)n0*FEAT;
    float acc0=bv, acc1=bv, acc2=bv, acc3=bv;
    #pragma unroll
    for (int k = 0; k < FEAT; k++){
      const float wv = wreg[k];
      acc0 += xr[k]*wv;
      acc1 += xr[FEAT+k]*wv;
      acc2 += xr[2*FEAT+k]*wv;
      acc3 += xr[3*FEAT+k]*wv;
    }
    if (m == 0){
      out_rel_b[(size_t)(n0+0)*HID + lane] = f2bf(acc0);
      out_rel_b[(size_t)(n0+1)*HID + lane] = f2bf(acc1);
      out_rel_b[(size_t)(n0+2)*HID + lane] = f2bf(acc2);
      out_rel_b[(size_t)(n0+3)*HID + lane] = f2bf(acc3);
    } else {
      out_root[(size_t)(n0+0)*HID + lane] = acc0;
      out_root[(size_t)(n0+1)*HID + lane] = acc1;
      out_root[(size_t)(n0+2)*HID + lane] = acc2;
      out_root[(size_t)(n0+3)*HID + lane] = acc3;
    }
  }
}

// ============ conv5: dual GEMM, K=256 (split-K), M=64; rel out in bf16 =======
__global__ __launch_bounds__(256) void conv5_gemm(
    const float* __restrict__ X, const float* __restrict__ Wrel,
    const float* __restrict__ Wroot, const float* __restrict__ bias,
    ushort_t* __restrict__ out_rel_b, float* __restrict__ out_root)
{
  const int w    = __builtin_amdgcn_readfirstlane(threadIdx.x >> 6);
  const int lane = threadIdx.x & 63;
  const int m = w >> 1, q = w & 1;
  const float* Wm = (m ? Wroot : Wrel) + (size_t)q*128*HID;
  float wreg[128];
  #pragma unroll
  for (int k = 0; k < 128; k++) wreg[k] = Wm[k*HID + lane];
  __shared__ float part[2][2][4][64];
  for (int base = blockIdx.x*4; base < N_NODES; base += gridDim.x*4){
    const float* __restrict__ xr = X + (size_t)base*HH + q*128;
    float acc0=0, acc1=0, acc2=0, acc3=0;
    #pragma unroll
    for (int k = 0; k < 128; k++){
      const float wv = wreg[k];
      acc0 += xr[k]*wv;
      acc1 += xr[HH+k]*wv;
      acc2 += xr[2*HH+k]*wv;
      acc3 += xr[3*HH+k]*wv;
    }
    __syncthreads();
    part[m][q][0][lane]=acc0; part[m][q][1][lane]=acc1;
    part[m][q][2][lane]=acc2; part[m][q][3][lane]=acc3;
    __syncthreads();
    #pragma unroll
    for (int t = threadIdx.x; t < 512; t += 256){
      int mm = t >> 8, ii = (t >> 6) & 3, cc = t & 63;
      float v = part[mm][0][ii][cc] + part[mm][1][ii][cc];
      if (mm) out_root[(size_t)(base+ii)*HID + cc] = v + bias[cc];
      else    out_rel_b[(size_t)(base+ii)*HID + cc] = f2bf(v);
    }
  }
}

// ============ GAT transform: xl(bf16) = h1@Wg + head dots ====================
__global__ __launch_bounds__(256) void k3_gat_transform(
    const float* __restrict__ h1, const float* __restrict__ Wg,
    const float* __restrict__ att_src, const float* __restrict__ att_dst,
    ushort_t* __restrict__ xlb, float* __restrict__ a_s, float* __restrict__ a_d)
{
  const int hc = threadIdx.x, h = hc >> 6, lane = hc & 63;
  float wreg[HID];
  #pragma unroll
  for (int k = 0; k < HID; k++) wreg[k] = Wg[k*HH + hc];
  const float asv = att_src[h*HID + lane];
  const float adv = att_dst[h*HID + lane];
  for (int base = blockIdx.x*4; base < N_NODES; base += gridDim.x*4){
    const float* __restrict__ xr = h1 + (size_t)base*HID;
    float acc0=0, acc1=0, acc2=0, acc3=0;
    #pragma unroll
    for (int k = 0; k < HID; k++){
      const float wv = wreg[k];
      acc0 += xr[k]*wv;
      acc1 += xr[HID+k]*wv;
      acc2 += xr[2*HID+k]*wv;
      acc3 += xr[3*HID+k]*wv;
    }
    float accs[4] = {acc0, acc1, acc2, acc3};
    #pragma unroll
    for (int i = 0; i < 4; i++){
      xlb[(size_t)(base+i)*HH + hc] = f2bf(accs[i]);
      float s1 = accs[i]*asv, s2 = accs[i]*adv;
      #pragma unroll
      for (int off = 32; off; off >>= 1){
        s1 += __shfl_xor(s1, off, 64);
        s2 += __shfl_xor(s2, off, 64);
      }
      if (lane == 0){
        a_s[(base+i)*HEADS + h] = s1;
        a_d[(base+i)*HEADS + h] = s2;
      }
    }
  }
}

// ---------------- CSR build --------------------------------------------------
__global__ __launch_bounds__(256) void k_hist(const int* __restrict__ dst, int* __restrict__ deg)
{
  int e = blockIdx.x*256 + threadIdx.x;
  if (e < N_EDGES) atomicAdd(&deg[dst[e]], 1);
}

__global__ __launch_bounds__(1024) void k_scan(const int* __restrict__ deg,
                                               int* __restrict__ row_start,
                                               int* __restrict__ cursor)
{
  const int SEG = (N_NODES + 1023) / 1024;     // 25
  const int t = threadIdx.x, lane = t & 63, wid = t >> 6;
  int begin = t*SEG, end = begin+SEG; if (end > N_NODES) end = N_NODES;
  if (begin > N_NODES) begin = N_NODES;
  int lsum = 0;
  for (int i = begin; i < end; i++) lsum += deg[i];
  int v = lsum;
  #pragma unroll
  for (int off = 1; off < 64; off <<= 1){
    int u = __shfl_up(v, off, 64);
    if (lane >= off) v += u;
  }
  __shared__ int wsum[16];
  __shared__ int wpre[16];
  if (lane == 63) wsum[wid] = v;
  __syncthreads();
  if (t == 0){
    int run = 0;
    for (int w = 0; w < 16; w++){ wpre[w] = run; run += wsum[w]; }
  }
  __syncthreads();
  int excl = wpre[wid] + v - lsum;
  int run = excl;
  for (int i = begin; i < end; i++){
    row_start[i] = run; cursor[i] = run;
    run += deg[i];
  }
  if (t == 0) row_start[N_NODES] = N_EDGES;
}

__global__ __launch_bounds__(256) void k_fill(const int* __restrict__ src,
                                              const int* __restrict__ dst,
                                              int* __restrict__ cursor,
                                              int* __restrict__ perm_src)
{
  int e = blockIdx.x*256 + threadIdx.x;
  if (e >= N_EDGES) return;
  int pos = atomicAdd(&cursor[dst[e]], 1);
  perm_src[pos] = src[e];
}

// -------- gather agg (bf16 feat): out = relu(root + sum_in feat[src]) --------
// wave per node; 8-lane groups x 8 edges in flight; 16B (8 bf16) per lane.
__global__ __launch_bounds__(256) void k_aggb(
    const int* __restrict__ row_start, const int* __restrict__ perm_src,
    const uint4* __restrict__ featb, const float4* __restrict__ root4,
    float4* __restrict__ out4)
{
  const int node = blockIdx.x*4 + (threadIdx.x >> 6);
  if (node >= N_NODES) return;
  const int lane = threadIdx.x & 63;
  const int eg = lane >> 3, cl = lane & 7;
  const int s0 = row_start[node], deg = row_start[node+1] - s0;
  float a0=0,a1=0,a2=0,a3=0,a4=0,a5=0,a6=0,a7=0;
  for (int e0 = 0; e0 < deg; e0 += 8){
    const int e = e0 + eg;
    if (e < deg){
      int s = perm_src[s0 + e];
      uint4 r = featb[(size_t)s*8 + cl];
      a0 += BF_LO(r.x); a1 += BF_HI(r.x);
      a2 += BF_LO(r.y); a3 += BF_HI(r.y);
      a4 += BF_LO(r.z); a5 += BF_HI(r.z);
      a6 += BF_LO(r.w); a7 += BF_HI(r.w);
    }
  }
  #pragma unroll
  for (int off = 8; off <= 32; off <<= 1){
    a0 += __shfl_xor(a0, off, 64); a1 += __shfl_xor(a1, off, 64);
    a2 += __shfl_xor(a2, off, 64); a3 += __shfl_xor(a3, off, 64);
    a4 += __shfl_xor(a4, off, 64); a5 += __shfl_xor(a5, off, 64);
    a6 += __shfl_xor(a6, off, 64); a7 += __shfl_xor(a7, off, 64);
  }
  if (eg == 0){
    float4 r0 = root4[(size_t)node*16 + cl*2];
    float4 r1 = root4[(size_t)node*16 + cl*2 + 1];
    float4 o0, o1;
    o0.x = fmaxf(a0 + r0.x, 0.f); o0.y = fmaxf(a1 + r0.y, 0.f);
    o0.z = fmaxf(a2 + r0.z, 0.f); o0.w = fmaxf(a3 + r0.w, 0.f);
    o1.x = fmaxf(a4 + r1.x, 0.f); o1.y = fmaxf(a5 + r1.y, 0.f);
    o1.z = fmaxf(a6 + r1.z, 0.f); o1.w = fmaxf(a7 + r1.w, 0.f);
    out4[(size_t)node*16 + cl*2]     = o0;
    out4[(size_t)node*16 + cl*2 + 1] = o1;
  }
}

// ---- fused per-node GAT softmax+aggregate: single pass, no LDS, bf16 xl -----
__global__ __launch_bounds__(256) void k_gat_node(
    const int* __restrict__ row_start, const int* __restrict__ perm_src,
    const uint4* __restrict__ xlb, const float* __restrict__ a_s,
    const float* __restrict__ a_d, const float* __restrict__ bg,
    float* __restrict__ h2)
{
  const int d = blockIdx.x;
  const int tid = threadIdx.x, h = tid >> 6, lane = tid & 63;
  const int eg = lane >> 3, cl = lane & 7;
  const int s0 = row_start[d], deg = row_start[d+1] - s0;
  const float ad = a_d[d*HEADS + h];
  float a0=0,a1=0,a2=0,a3=0,a4=0,a5=0,a6=0,a7=0;
  float dsum = 0.f;
  for (int e0 = 0; e0 < deg; e0 += 8){
    const int e = e0 + eg;
    if (e < deg){
      int s = perm_src[s0 + e];
      float p = __expf(lrelu(a_s[s*HEADS + h] + ad));
      uint4 r = xlb[(size_t)s*32 + h*8 + cl];
      dsum += p;
      a0 += p*BF_LO(r.x); a1 += p*BF_HI(r.x);
      a2 += p*BF_LO(r.y); a3 += p*BF_HI(r.y);
      a4 += p*BF_LO(r.z); a5 += p*BF_HI(r.z);
      a6 += p*BF_LO(r.w); a7 += p*BF_HI(r.w);
    }
  }
  // denom: one lane per 8-lane group carries its group's sum; full-wave reduce
  float dpart = (cl == 0) ? dsum : 0.f;
  #pragma unroll
  for (int off = 32; off; off >>= 1) dpart += __shfl_xor(dpart, off, 64);
  // feature reduce across the 8 edge-groups (lane bits 3..5)
  #pragma unroll
  for (int off = 8; off <= 32; off <<= 1){
    a0 += __shfl_xor(a0, off, 64); a1 += __shfl_xor(a1, off, 64);
    a2 += __shfl_xor(a2, off, 64); a3 += __shfl_xor(a3, off, 64);
    a4 += __shfl_xor(a4, off, 64); a5 += __shfl_xor(a5, off, 64);
    a6 += __shfl_xor(a6, off, 64); a7 += __shfl_xor(a7, off, 64);
  }
  if (eg == 0){
    const float pself = __expf(lrelu(a_s[d*HEADS + h] + ad));
    const float inv = 1.f / (dpart + pself);
    uint4 r = xlb[(size_t)d*32 + h*8 + cl];
    a0 += pself*BF_LO(r.x); a1 += pself*BF_HI(r.x);
    a2 += pself*BF_LO(r.y); a3 += pself*BF_HI(r.y);
    a4 += pself*BF_LO(r.z); a5 += pself*BF_HI(r.z);
    a6 += pself*BF_LO(r.w); a7 += pself*BF_HI(r.w);
    const int col0 = h*HID + cl*8;
    float4 o0, o1;
    o0.x = fmaxf(a0*inv + bg[col0+0], 0.f);
    o0.y = fmaxf(a1*inv + bg[col0+1], 0.f);
    o0.z = fmaxf(a2*inv + bg[col0+2], 0.f);
    o0.w = fmaxf(a3*inv + bg[col0+3], 0.f);
    o1.x = fmaxf(a4*inv + bg[col0+4], 0.f);
    o1.y = fmaxf(a5*inv + bg[col0+5], 0.f);
    o1.z = fmaxf(a6*inv + bg[col0+6], 0.f);
    o1.w = fmaxf(a7*inv + bg[col0+7], 0.f);
    float4* op = (float4*)(h2 + (size_t)d*HH + col0);
    op[0] = o0; op[1] = o1;
  }
}

// ---------------- pool: run-length segment reduce over sorted batch ----------
__global__ __launch_bounds__(256) void k_pool(
    const float* __restrict__ h3, const int* __restrict__ batch,
    float* __restrict__ g)
{
  const int w = blockIdx.x*4 + (threadIdx.x >> 6);
  const int j = threadIdx.x & 63;
  int n0 = w*64;
  if (n0 >= N_NODES) return;
  int n1 = min(n0+64, N_NODES);
  float acc = 0.f;
  int cur = batch[n0];
  for (int n = n0; n < n1; n++){
    int b = batch[n];
    if (b != cur){ atomicAdd(&g[cur*HID + j], acc); acc = 0.f; cur = b; }
    acc += h3[n*HID + j];
  }
  atomicAdd(&g[cur*HID + j], acc);
}

__global__ __launch_bounds__(256) void k_head(
    const float* __restrict__ g, const float* __restrict__ W1,
    const float* __restrict__ b1, const float* __restrict__ W2,
    const float* __restrict__ b2, float* __restrict__ out)
{
  __shared__ float gs[NUM_GRAPHS*HID];
  __shared__ float hh[NUM_GRAPHS*HID];
  for (int i = threadIdx.x; i < NUM_GRAPHS*HID; i += 256) gs[i] = g[i];
  __syncthreads();
  for (int t = threadIdx.x; t < NUM_GRAPHS*HID; t += 256){
    int b = t >> 6, j = t & 63;
    float acc = b1[j];
    for (int k = 0; k < HID; k++) acc += gs[b*HID+k]*W1[k*HID+j];
    hh[t] = fmaxf(acc, 0.f);
  }
  __syncthreads();
  for (int t = threadIdx.x; t < NUM_GRAPHS*2; t += 256){
    int b = t >> 1, c = t & 1;
    float acc = b2[c];
    for (int k = 0; k < HID; k++) acc += hh[b*HID+k]*W2[k*2+c];
    out[t] = 1.f / (1.f + __expf(-acc));
  }
}

extern "C" void kernel_launch(void* const* d_in, const int* in_sizes, int n_in,
                              void* d_out, int out_size, void* d_ws, size_t ws_size,
                              hipStream_t stream)
{
  const float* x       = (const float*)d_in[0];
  const int*   ei      = (const int*)d_in[1];
  const int*   batch   = (const int*)d_in[2];
  const float* W1_rel  = (const float*)d_in[3];
  const float* b1      = (const float*)d_in[4];
  const float* W1_root = (const float*)d_in[5];
  const float* Wg      = (const float*)d_in[6];
  const float* att_src = (const float*)d_in[7];
  const float* att_dst = (const float*)d_in[8];
  const float* bg      = (const float*)d_in[9];
  const float* W5_rel  = (const float*)d_in[10];
  const float* b5      = (const float*)d_in[11];
  const float* W5_root = (const float*)d_in[12];
  const float* W_fc1   = (const float*)d_in[13];
  const float* b_fc1   = (const float*)d_in[14];
  const float* W_fc2   = (const float*)d_in[15];
  const float* b_fc2   = (const float*)d_in[16];
  const int* src = ei;
  const int* dst = ei + N_EDGES;

  // ---- workspace layout, FLOAT (4-byte) units, all 16B-aligned -------------
  // xr_b  : bf16 N*64  = 1.6M ushort = 800000 f-units   [0,       800000)
  // hB    : f32  N*64  = 1.6M                           [800000,  2400000)
  // xlb   : bf16 N*256 = 6.4M ushort = 3200000 f-units  [2400000, 5600000)
  // a_s   : f32  N*4 (+pad)                             [5600000, 5700000)
  // a_d   : f32  N*4 (+pad)                             [5700000, 5800000)
  // h2    : f32  N*256 = 6.4M                           [5800000, 12200000)
  // g     : f32  64*64 = 4096                           [12200000,12204096)
  // ints  : deg/row_st/cursor/perm_src                  [12204096, ...)
  float* ws    = (float*)d_ws;
  ushort_t* xr_b = (ushort_t*)ws;
  float* hB    = ws +   800000;
  ushort_t* xlb = (ushort_t*)(ws + 2400000);
  float* a_s   = ws +  5600000;
  float* a_d   = ws +  5700000;
  float* h2    = ws +  5800000;
  float* g     = ws + 12200000;
  int*   ib    = (int*)(ws + 12204096); // deg adjacent to g -> single memset
  int* deg      = ib;                   // 25000
  int* row_st   = ib + 25000;           // 25001 (+pad)
  int* cursor   = ib + 50016;           // 25000
  int* perm_src = ib + 75016;           // 400000
  float* out   = (float*)d_out;

  // CSR build (+ zero g in the same memset)
  hipMemsetAsync(g, 0, (4096 + N_NODES)*sizeof(float), stream);
  k_hist<<<(N_EDGES+255)/256,256,0,stream>>>(dst, deg);
  k_scan<<<1,1024,0,stream>>>(deg, row_st, cursor);
  k_fill<<<(N_EDGES+255)/256,256,0,stream>>>(src, dst, cursor, perm_src);

  // conv1
  conv1_gemm<<<1024,256,0,stream>>>(x, W1_rel, W1_root, b1, xr_b, hB);
  k_aggb<<<(N_NODES+3)/4,256,0,stream>>>(row_st, perm_src,
      (const uint4*)xr_b, (const float4*)hB, (float4*)hB);

  // GAT
  k3_gat_transform<<<1024,256,0,stream>>>(hB, Wg, att_src, att_dst, xlb, a_s, a_d);
  k_gat_node<<<N_NODES,256,0,stream>>>(row_st, perm_src,
      (const uint4*)xlb, a_s, a_d, bg, h2);

  // conv5
  conv5_gemm<<<1024,256,0,stream>>>(h2, W5_rel, W5_root, b5, xr_b, hB);
  k_aggb<<<(N_NODES+3)/4,256,0,stream>>>(row_st, perm_src,
      (const uint4*)xr_b, (const float4*)hB, (float4*)hB);

  // pool + head
  k_pool<<<(N_NODES/256)+1,256,0,stream>>>(hB, batch, g);
  k_head<<<1,256,0,stream>>>(g, W_fc1, b_fc1, W_fc2, b_fc2, out);
}